// Round 2
// baseline (4023.603 us; speedup 1.0000x reference)
//
#include <hip/hip_runtime.h>
#include <hip/hip_bf16.h>

// LSTM: B=1024, SEQ=128, H=1024, NCLS=10, IN_DIM=1.
// PERSISTENT kernel (plain launch, 256 WGs on 256 CUs -> co-resident by
// capacity: 64KiB LDS, 152 VGPR, 256 thr => >=1 WG/CU). All 128 time steps in
// ONE dispatch; hand-rolled two-level grid barrier between steps (8 group
// counters -> master -> gen) with agent-scope fences for cross-XCD h
// visibility. c-state lives in REGISTERS across all steps -> zero c traffic.
// GEMM per step is the harness-verified structure: fp16 MFMA 16x16x32,
// 128x128 tile, 2x2 waves of 64x64 (4x4 acc). A (h_in): LDS double-buffered
// BK=128 (64 KiB), XOR-swizzle, staged via global_load_lds w=16. B (weights):
// prepacked FRAGMENT-MAJOR, 1KB coalesced global_load_dwordx4 per fragment,
// register-pipelined; stays L2/L3-resident since c traffic is gone.

#define HDIM 1024
#define SEQ 128
#define NCLS 10
#define NWG 256

using half8   = __attribute__((ext_vector_type(8))) _Float16;
using floatx4 = __attribute__((ext_vector_type(4))) float;

#define GLOBAL_AS const __attribute__((address_space(1))) void*
#define LDS_AS __attribute__((address_space(3))) void*

__device__ __forceinline__ float fast_sig(float x) {
    return __builtin_amdgcn_rcpf(1.f + __expf(-x));
}
__device__ __forceinline__ float fast_tanh(float x) {
    return 1.f - 2.f * __builtin_amdgcn_rcpf(__expf(2.f * x) + 1.f);
}

// ---------------------------------------------------------------------------
// Prepack fp32->fp16, FRAGMENT-MAJOR chunks of 1 KB (layout unchanged).
// Block 0 additionally zeroes the grid-barrier state (runs before the
// persistent kernel on the same stream, so ordering is guaranteed).
// ---------------------------------------------------------------------------
__global__ void prepack_kernel(const float* __restrict__ wgh,
                               const float* __restrict__ wih,
                               const float* __restrict__ wfh,
                               const float* __restrict__ woh,
                               _Float16* __restrict__ Wp,
                               int* __restrict__ bar) {
    if (blockIdx.x == 0) {
        for (int i = threadIdx.x; i < 512; i += 64) bar[i] = 0;
    }
    const int chunk = blockIdx.x;        // 0..8191
    const int l = threadIdx.x;           // 0..63
    const int ng = chunk & 7;
    const int kc = (chunk >> 3) & 3;
    const int kt = (chunk >> 5) & 7;
    const int u  = chunk >> 8;
    const int quad = l >> 4, nl = l & 15;
    const int c = ng * 16 + nl;
    const int gate = (c >> 4) & 3;
    const int j = u * 32 + (c >> 6) * 16 + (c & 15);
    const int k0 = kt * 128 + kc * 32 + quad * 8;
    const float* src = (gate == 0) ? wgh : (gate == 1) ? wih
                     : (gate == 2) ? wfh : woh;
    src += (size_t)j * HDIM + k0;
    float4 v0 = *(const float4*)(src);
    float4 v1 = *(const float4*)(src + 4);
    union { _Float16 h[8]; uint4 u4; } cv;
    cv.h[0] = (_Float16)v0.x; cv.h[1] = (_Float16)v0.y;
    cv.h[2] = (_Float16)v0.z; cv.h[3] = (_Float16)v0.w;
    cv.h[4] = (_Float16)v1.x; cv.h[5] = (_Float16)v1.y;
    cv.h[6] = (_Float16)v1.z; cv.h[7] = (_Float16)v1.w;
    *(uint4*)(Wp + (size_t)chunk * 512 + l * 8) = cv.u4;
}

// ---------------------------------------------------------------------------
// Two-level grid barrier. bar layout (ints): group g counter at [g*32]
// (g = blockIdx&7, 32 blocks/group, 128B apart), master at [320], gen at [352].
// Chain: per-block release fence (waitcnt + L2 writeback) -> group counter
// acq_rel RMW -> leader acq_rel RMW on master -> flipper acquire fence, reset
// counters, release-store gen -> spinners relaxed-load gen, acquire fence
// (L2/L1 invalidate) -> fresh h_in reads. All atomics agent-scope (execute at
// the coherence point, cross-XCD safe).
// ---------------------------------------------------------------------------
__device__ __forceinline__ void grid_sync(int* bar, int target) {
    __syncthreads();                       // per-wave vmcnt drain of h stores
    if (threadIdx.x == 0) {
        __builtin_amdgcn_fence(__ATOMIC_RELEASE, "agent");   // publish h_out
        const int g = (blockIdx.x & 7) * 32;
        int v = __hip_atomic_fetch_add(&bar[g], 1, __ATOMIC_ACQ_REL,
                                       __HIP_MEMORY_SCOPE_AGENT);
        if (v == 31) {                     // group leader (last arriver)
            int m = __hip_atomic_fetch_add(&bar[320], 1, __ATOMIC_ACQ_REL,
                                           __HIP_MEMORY_SCOPE_AGENT);
            if (m == 7) {                  // flipper (last group)
                __builtin_amdgcn_fence(__ATOMIC_ACQUIRE, "agent");
                #pragma unroll
                for (int i = 0; i < 8; ++i)
                    __hip_atomic_store(&bar[i * 32], 0, __ATOMIC_RELAXED,
                                       __HIP_MEMORY_SCOPE_AGENT);
                __hip_atomic_store(&bar[320], 0, __ATOMIC_RELAXED,
                                   __HIP_MEMORY_SCOPE_AGENT);
                __hip_atomic_store(&bar[352], target, __ATOMIC_RELEASE,
                                   __HIP_MEMORY_SCOPE_AGENT);
            }
        }
        while (__hip_atomic_load(&bar[352], __ATOMIC_RELAXED,
                                 __HIP_MEMORY_SCOPE_AGENT) < target)
            __builtin_amdgcn_s_sleep(2);
        __builtin_amdgcn_fence(__ATOMIC_ACQUIRE, "agent");   // inv: fresh h_in
    }
    __syncthreads();
}

struct PParams {
    _Float16* hb0; _Float16* hb1;
    const _Float16* Wp; const float* x;
    const float* wgx; const float* wix; const float* wfx; const float* wox;
    const float* bg;  const float* bi;  const float* bf;  const float* bo;
    int* bar;
};

// ---------------------------------------------------------------------------
// Persistent LSTM: 256 WGs x 256 thr (plain launch, co-resident by capacity).
// Tile 128 batch x 128 gate-cols per WG, fixed across all 128 steps;
// c-state in registers.
// ---------------------------------------------------------------------------
__global__ __launch_bounds__(256, 1) void lstm_persist(PParams p) {
    __shared__ _Float16 lA[2][128 * 128];   // 2 x 32 KB (A tiles, BK=128)

    const _Float16* __restrict__ Wpp = p.Wp;
    const float* __restrict__ x = p.x;
    int* bar = p.bar;

    const int blk = blockIdx.x;
    const int u   = (blk & 7) * 4 + ((blk >> 3) & 3);  // unit-tile, XCD-local
    const int bc  = blk >> 5;
    const int b0  = bc * 128;
    const int tid = threadIdx.x;
    const int wv  = tid >> 6;
    const int l   = tid & 63;
    const int lane15 = l & 15;
    const int quad   = l >> 4;
    const int rf     = lane15 & 7;
    const int wr = wv >> 1, wc = wv & 1;

    // this lane's unit j; epilogue constants (hoisted once for all steps)
    const int j = u * 32 + wc * 16 + lane15;
    const float wgx_ = p.wgx[j], wix_ = p.wix[j], wfx_ = p.wfx[j], wox_ = p.wox[j];
    const float bg_ = p.bg[j], bi_ = p.bi[j], bf_ = p.bf[j], bo_ = p.bo[j];

    // A staging constants: lane l covers row l>>4, slot l&15 per instruction.
    const int rowA = l >> 4;
    const int kbE  = lane15 ^ rowA;          // swizzled kb, even i
    const int gE   = rowA * HDIM + kbE * 8;
    const int gO   = rowA * HDIM + (kbE ^ 4) * 8;   // odd i
    const int lbase = wv * 4096 + l * 8;

    // B fragment pointer: frag(kt,kc,nt) at Bl + ((kt*4+kc)*8+nt)*512 halves
    const _Float16* Bl = Wpp + ((size_t)u * 256 + wc * 4) * 512 + l * 8;

    float creg[4][4] = {};   // persistent cell state: 16 f32/lane

    for (int t = 0; t < SEQ; ++t) {
        if (t) grid_sync(bar, t);            // h_out(t-1) visible grid-wide

        const _Float16* h_in  = (t & 1) ? p.hb0 : p.hb1;
        _Float16*       h_out = (t & 1) ? p.hb1 : p.hb0;

        // prefetch x(t) for this lane's 16 batch rows (hidden under GEMM)
        float xr[4][4];
        #pragma unroll
        for (int mt = 0; mt < 4; ++mt)
            #pragma unroll
            for (int r = 0; r < 4; ++r) {
                const int m = wr * 64 + mt * 16 + quad * 4 + r;
                xr[mt][r] = x[(size_t)(b0 + m) * SEQ + t];
            }

        floatx4 acc[4][4] = {};

        if (t > 0) {
            const _Float16* Abase = h_in + (size_t)b0 * HDIM + (size_t)wv * 32 * HDIM;

            half8 bp0[2][4], bp1[2][4];   // kc-pair register pipeline

            // prologue: stage A(kt=0) into lA[0]; load B kc{0,1} of kt0
            #pragma unroll
            for (int i = 0; i < 8; ++i) {
                const int go = i * 4 * HDIM + ((i & 1) ? gO : gE);
                __builtin_amdgcn_global_load_lds((GLOBAL_AS)(Abase + go),
                                                 (LDS_AS)(&lA[0][lbase + i * 512]), 16, 0, 0);
            }
            #pragma unroll
            for (int kc = 0; kc < 2; ++kc)
                #pragma unroll
                for (int nt = 0; nt < 4; ++nt)
                    bp0[kc][nt] = *(const half8*)(Bl + ((0 * 4 + kc) * 8 + nt) * 512);
            __syncthreads();

            #pragma unroll 2
            for (int kt = 0; kt < 8; ++kt) {
                const int cur = kt & 1;
                // issue B kc{2,3} of this kt
                #pragma unroll
                for (int kc = 0; kc < 2; ++kc)
                    #pragma unroll
                    for (int nt = 0; nt < 4; ++nt)
                        bp1[kc][nt] = *(const half8*)(Bl + ((kt * 4 + 2 + kc) * 8 + nt) * 512);
                // stage A(kt+1) into the other buffer
                if (kt < 7) {
                    const int k0 = (kt + 1) * 128;
                    #pragma unroll
                    for (int i = 0; i < 8; ++i) {
                        const int go = i * 4 * HDIM + ((i & 1) ? gO : gE);
                        __builtin_amdgcn_global_load_lds(
                            (GLOBAL_AS)(Abase + go + k0),
                            (LDS_AS)(&lA[1 - cur][lbase + i * 512]), 16, 0, 0);
                    }
                }
                const _Float16* bufA = &lA[cur][0];
                // compute kc 0,1 with bp0
                #pragma unroll
                for (int kc = 0; kc < 2; ++kc) {
                    const int slot = ((kc * 4 + quad) ^ rf) * 8;
                    half8 afr[4];
                    #pragma unroll
                    for (int mt = 0; mt < 4; ++mt)
                        afr[mt] = *(const half8*)(bufA + (wr * 64 + mt * 16 + lane15) * 128 + slot);
                    #pragma unroll
                    for (int mt = 0; mt < 4; ++mt)
                        #pragma unroll
                        for (int nt = 0; nt < 4; ++nt)
                            acc[mt][nt] = __builtin_amdgcn_mfma_f32_16x16x32_f16(
                                afr[mt], bp0[kc][nt], acc[mt][nt], 0, 0, 0);
                }
                // issue B kc{0,1} of kt+1
                if (kt < 7) {
                    #pragma unroll
                    for (int kc = 0; kc < 2; ++kc)
                        #pragma unroll
                        for (int nt = 0; nt < 4; ++nt)
                            bp0[kc][nt] = *(const half8*)(Bl + (((kt + 1) * 4 + kc) * 8 + nt) * 512);
                }
                // compute kc 2,3 with bp1
                #pragma unroll
                for (int kc = 0; kc < 2; ++kc) {
                    const int slot = (((kc + 2) * 4 + quad) ^ rf) * 8;
                    half8 afr[4];
                    #pragma unroll
                    for (int mt = 0; mt < 4; ++mt)
                        afr[mt] = *(const half8*)(bufA + (wr * 64 + mt * 16 + lane15) * 128 + slot);
                    #pragma unroll
                    for (int mt = 0; mt < 4; ++mt)
                        #pragma unroll
                        for (int nt = 0; nt < 4; ++nt)
                            acc[mt][nt] = __builtin_amdgcn_mfma_f32_16x16x32_f16(
                                afr[mt], bp1[kc][nt], acc[mt][nt], 0, 0, 0);
                }
                __syncthreads();
            }
        }

        // fused LSTM cell epilogue: lane holds all 4 gates of (batch m, unit j);
        // c stays in registers across steps.
        #pragma unroll
        for (int mt = 0; mt < 4; ++mt) {
            #pragma unroll
            for (int r = 0; r < 4; ++r) {
                const int m = wr * 64 + mt * 16 + quad * 4 + r;
                const float xt = xr[mt][r];
                float pg = acc[mt][0][r] + xt * wgx_ + bg_;
                float pi = acc[mt][1][r] + xt * wix_ + bi_;
                float pf = acc[mt][2][r] + xt * wfx_ + bf_;
                float po = acc[mt][3][r] + xt * wox_ + bo_;
                float g  = fast_tanh(pg);
                float ii = fast_sig(pi);
                float ff = fast_sig(pf);
                float oo = fast_sig(po);
                float cn = g * ii + creg[mt][r] * ff;
                creg[mt][r] = cn;
                h_out[(size_t)(b0 + m) * HDIM + j] = (_Float16)(fast_tanh(cn) * oo);
            }
        }
    }
}

// ---------------------------------------------------------------------------
// logits = h_last @ w_ph^T + bias_p. One wave per batch row.
// ---------------------------------------------------------------------------
__global__ void logits_kernel(const _Float16* __restrict__ h,
                              const float* __restrict__ wph,
                              const float* __restrict__ bp,
                              float* __restrict__ out) {
    const int w = (blockIdx.x * blockDim.x + threadIdx.x) >> 6; // 0..1023
    const int l = threadIdx.x & 63;
    float accv[NCLS];
    #pragma unroll
    for (int c = 0; c < NCLS; ++c) accv[c] = 0.f;
    for (int k = l; k < HDIM; k += 64) {
        float hv = (float)h[(size_t)w * HDIM + k];
        #pragma unroll
        for (int c = 0; c < NCLS; ++c)
            accv[c] += hv * wph[c * HDIM + k];
    }
    #pragma unroll
    for (int c = 0; c < NCLS; ++c) {
        float v = accv[c];
        #pragma unroll
        for (int off = 32; off > 0; off >>= 1)
            v += __shfl_down(v, off, 64);
        if (l == 0) out[w * NCLS + c] = v + bp[c];
    }
}

extern "C" void kernel_launch(void* const* d_in, const int* in_sizes, int n_in,
                              void* d_out, int out_size, void* d_ws, size_t ws_size,
                              hipStream_t stream) {
    const float* x   = (const float*)d_in[0];
    const float* wgx = (const float*)d_in[1];
    const float* wgh = (const float*)d_in[2];
    const float* wix = (const float*)d_in[3];
    const float* wih = (const float*)d_in[4];
    const float* wfx = (const float*)d_in[5];
    const float* wfh = (const float*)d_in[6];
    const float* wox = (const float*)d_in[7];
    const float* woh = (const float*)d_in[8];
    const float* wph = (const float*)d_in[9];
    const float* bg  = (const float*)d_in[10];
    const float* bi  = (const float*)d_in[11];
    const float* bf  = (const float*)d_in[12];
    const float* bo  = (const float*)d_in[13];
    const float* bp  = (const float*)d_in[14];
    float* out = (float*)d_out;

    char* ws = (char*)d_ws;
    _Float16* Wp    = (_Float16*)(ws);               // 0..8 MB (8192 x 1KB)
    _Float16* hbuf0 = (_Float16*)(ws + (8u << 20));  // 8..10 MB
    _Float16* hbuf1 = (_Float16*)(ws + (10u << 20)); // 10..12 MB
    int*      bar   = (int*)(ws + (12u << 20));      // barrier state (2 KB)

    prepack_kernel<<<8192, 64, 0, stream>>>(wgh, wih, wfh, woh, Wp, bar);

    PParams pp;
    pp.hb0 = hbuf0; pp.hb1 = hbuf1; pp.Wp = Wp; pp.x = x;
    pp.wgx = wgx; pp.wix = wix; pp.wfx = wfx; pp.wox = wox;
    pp.bg = bg; pp.bi = bi; pp.bf = bf; pp.bo = bo;
    pp.bar = bar;
    lstm_persist<<<NWG, 256, 0, stream>>>(pp);

    logits_kernel<<<256, 256, 0, stream>>>(hbuf1, wph, bp, out);  // t=127 -> hbuf1
}

// Round 3
// 2291.236 us; speedup vs baseline: 1.7561x; 1.7561x over previous
//
#include <hip/hip_runtime.h>
#include <hip/hip_bf16.h>

// LSTM: B=1024, SEQ=128, H=1024, NCLS=10, IN_DIM=1.
// PERSISTENT kernel, plain <<<256,256>>> launch (co-resident by capacity).
// All 128 steps in one dispatch. Cross-XCD h visibility WITHOUT cache fences:
//   - h_out stores:  global_store_short sc0 sc1  (write-through to MALL)
//   - h_in staging:  global_load_lds aux=17 (SC0|SC1, bypass L1+L2, read MALL)
//   - barrier: monotonic two-level counters, RELAXED agent-scope atomics
//     (MALL-executed, placement-independent), explicit vmcnt(0) drain.
// => NO buffer_wbl2 / buffer_inv anywhere: the per-XCD 1 MB weight panel
// stays L2-resident across all 128 steps (round-2 counters showed the agent
// fences refetched 8.2 MB/step = the whole weight matrix).
// c-state in registers. GEMM per step: fp16 MFMA 16x16x32, 128x128 tile,
// 2x2 waves of 64x64 (4x4 acc), LDS double-buffered A (BK=128, XOR-swizzle,
// global_load_lds w=16), B prepacked fragment-major register pipeline.

#define HDIM 1024
#define SEQ 128
#define NCLS 10
#define NWG 256

using half8   = __attribute__((ext_vector_type(8))) _Float16;
using floatx4 = __attribute__((ext_vector_type(4))) float;

#define GLOBAL_AS const __attribute__((address_space(1))) void*
#define LDS_AS __attribute__((address_space(3))) void*

__device__ __forceinline__ float fast_sig(float x) {
    return __builtin_amdgcn_rcpf(1.f + __expf(-x));
}
__device__ __forceinline__ float fast_tanh(float x) {
    return 1.f - 2.f * __builtin_amdgcn_rcpf(__expf(2.f * x) + 1.f);
}

// System-scope (MALL write-through) fp16 store: sc0 sc1 -> no L2 copy exists,
// readers that bypass L2 see it without any cache-maintenance fence.
__device__ __forceinline__ void store_h_sys(_Float16* p, float v) {
    union { _Float16 h; unsigned short s; } u;
    u.h = (_Float16)v;
    unsigned int w = u.s;
    asm volatile("global_store_short %0, %1, off sc0 sc1"
                 :: "v"(p), "v"(w) : "memory");
}

// ---------------------------------------------------------------------------
// Prepack fp32->fp16, FRAGMENT-MAJOR chunks of 1 KB (layout unchanged).
// Block 0 zeroes the grid-barrier state (stream order guarantees it precedes
// the persistent kernel; re-zeroed on every launch/graph replay).
// ---------------------------------------------------------------------------
__global__ void prepack_kernel(const float* __restrict__ wgh,
                               const float* __restrict__ wih,
                               const float* __restrict__ wfh,
                               const float* __restrict__ woh,
                               _Float16* __restrict__ Wp,
                               int* __restrict__ bar) {
    if (blockIdx.x == 0) {
        for (int i = threadIdx.x; i < 512; i += 64) bar[i] = 0;
    }
    const int chunk = blockIdx.x;        // 0..8191
    const int l = threadIdx.x;           // 0..63
    const int ng = chunk & 7;
    const int kc = (chunk >> 3) & 3;
    const int kt = (chunk >> 5) & 7;
    const int u  = chunk >> 8;
    const int quad = l >> 4, nl = l & 15;
    const int c = ng * 16 + nl;
    const int gate = (c >> 4) & 3;
    const int j = u * 32 + (c >> 6) * 16 + (c & 15);
    const int k0 = kt * 128 + kc * 32 + quad * 8;
    const float* src = (gate == 0) ? wgh : (gate == 1) ? wih
                     : (gate == 2) ? wfh : woh;
    src += (size_t)j * HDIM + k0;
    float4 v0 = *(const float4*)(src);
    float4 v1 = *(const float4*)(src + 4);
    union { _Float16 h[8]; uint4 u4; } cv;
    cv.h[0] = (_Float16)v0.x; cv.h[1] = (_Float16)v0.y;
    cv.h[2] = (_Float16)v0.z; cv.h[3] = (_Float16)v0.w;
    cv.h[4] = (_Float16)v1.x; cv.h[5] = (_Float16)v1.y;
    cv.h[6] = (_Float16)v1.z; cv.h[7] = (_Float16)v1.w;
    *(uint4*)(Wp + (size_t)chunk * 512 + l * 8) = cv.u4;
}

// ---------------------------------------------------------------------------
// Monotonic two-level grid barrier, NO cache maintenance. bar[g*32]: group
// counters (g = blk&7, 128B apart), bar[320]: master, bar[352]: generation.
// At barrier t: group counter goes 32(t-1) -> 32t (last arriver sees 32t-1),
// leaders push master 8(t-1) -> 8t (flipper sees 8t-1), flipper stores gen=t,
// spinners wait gen >= t. Monotonic => no reset race. All atomics relaxed,
// agent scope (execute at MALL: correct for any block->XCD placement, and no
// buffer_wbl2/buffer_inv is emitted). h data ordering is provided by the
// explicit vmcnt(0) drain (stores acked at MALL) + MALL-bypassing reads.
// ---------------------------------------------------------------------------
__device__ __forceinline__ void grid_sync(int* bar, int t) {
    asm volatile("s_waitcnt vmcnt(0)" ::: "memory");   // h stores reached MALL
    __syncthreads();
    if (threadIdx.x == 0) {
        const int g = (blockIdx.x & 7) * 32;
        int v = __hip_atomic_fetch_add(&bar[g], 1, __ATOMIC_RELAXED,
                                       __HIP_MEMORY_SCOPE_AGENT);
        if (v == 32 * t - 1) {             // group leader (last arriver)
            int m = __hip_atomic_fetch_add(&bar[320], 1, __ATOMIC_RELAXED,
                                           __HIP_MEMORY_SCOPE_AGENT);
            if (m == 8 * t - 1) {          // flipper (last group)
                __hip_atomic_store(&bar[352], t, __ATOMIC_RELAXED,
                                   __HIP_MEMORY_SCOPE_AGENT);
            }
        }
        while (__hip_atomic_load(&bar[352], __ATOMIC_RELAXED,
                                 __HIP_MEMORY_SCOPE_AGENT) < t)
            __builtin_amdgcn_s_sleep(1);
    }
    __syncthreads();
    asm volatile("" ::: "memory");
}

struct PParams {
    _Float16* hb0; _Float16* hb1;
    const _Float16* Wp; const float* x;
    const float* wgx; const float* wix; const float* wfx; const float* wox;
    const float* bg;  const float* bi;  const float* bf;  const float* bo;
    int* bar;
};

// ---------------------------------------------------------------------------
// Persistent LSTM: 256 WGs x 256 thr. Tile 128 batch x 128 gate-cols per WG,
// fixed across all 128 steps; c-state in registers. Weights stay L2-resident
// (1 MB/XCD with the blk&7 u-mapping; never invalidated).
// ---------------------------------------------------------------------------
__global__ __launch_bounds__(256, 1) void lstm_persist(PParams p) {
    __shared__ _Float16 lA[2][128 * 128];   // 2 x 32 KB (A tiles, BK=128)

    const _Float16* __restrict__ Wpp = p.Wp;
    const float* __restrict__ x = p.x;
    int* bar = p.bar;

    const int blk = blockIdx.x;
    const int u   = (blk & 7) * 4 + ((blk >> 3) & 3);  // unit-tile, XCD-local
    const int bc  = blk >> 5;
    const int b0  = bc * 128;
    const int tid = threadIdx.x;
    const int wv  = tid >> 6;
    const int l   = tid & 63;
    const int lane15 = l & 15;
    const int quad   = l >> 4;
    const int rf     = lane15 & 7;
    const int wr = wv >> 1, wc = wv & 1;

    // this lane's unit j; epilogue constants (hoisted once for all steps)
    const int j = u * 32 + wc * 16 + lane15;
    const float wgx_ = p.wgx[j], wix_ = p.wix[j], wfx_ = p.wfx[j], wox_ = p.wox[j];
    const float bg_ = p.bg[j], bi_ = p.bi[j], bf_ = p.bf[j], bo_ = p.bo[j];

    // A staging constants: lane l covers row l>>4, slot l&15 per instruction.
    const int rowA = l >> 4;
    const int kbE  = lane15 ^ rowA;          // swizzled kb, even i
    const int gE   = rowA * HDIM + kbE * 8;
    const int gO   = rowA * HDIM + (kbE ^ 4) * 8;   // odd i
    const int lbase = wv * 4096 + l * 8;

    // B fragment pointer: frag(kt,kc,nt) at Bl + ((kt*4+kc)*8+nt)*512 halves
    const _Float16* Bl = Wpp + ((size_t)u * 256 + wc * 4) * 512 + l * 8;

    float creg[4][4] = {};   // persistent cell state: 16 f32/lane

    for (int t = 0; t < SEQ; ++t) {
        if (t) grid_sync(bar, t);            // h_out(t-1) visible grid-wide

        const _Float16* h_in  = (t & 1) ? p.hb0 : p.hb1;
        _Float16*       h_out = (t & 1) ? p.hb1 : p.hb0;

        // prefetch x(t) for this lane's 16 batch rows (hidden under GEMM)
        float xr[4][4];
        #pragma unroll
        for (int mt = 0; mt < 4; ++mt)
            #pragma unroll
            for (int r = 0; r < 4; ++r) {
                const int m = wr * 64 + mt * 16 + quad * 4 + r;
                xr[mt][r] = x[(size_t)(b0 + m) * SEQ + t];
            }

        floatx4 acc[4][4] = {};

        if (t > 0) {
            const _Float16* Abase = h_in + (size_t)b0 * HDIM + (size_t)wv * 32 * HDIM;

            half8 bp0[2][4], bp1[2][4];   // kc-pair register pipeline

            // prologue: stage A(kt=0) into lA[0]; load B kc{0,1} of kt0.
            // aux=17 (SC0|SC1): bypass L1+L2, read at MALL -> always fresh.
            #pragma unroll
            for (int i = 0; i < 8; ++i) {
                const int go = i * 4 * HDIM + ((i & 1) ? gO : gE);
                __builtin_amdgcn_global_load_lds((GLOBAL_AS)(Abase + go),
                                                 (LDS_AS)(&lA[0][lbase + i * 512]), 16, 0, 17);
            }
            #pragma unroll
            for (int kc = 0; kc < 2; ++kc)
                #pragma unroll
                for (int nt = 0; nt < 4; ++nt)
                    bp0[kc][nt] = *(const half8*)(Bl + ((0 * 4 + kc) * 8 + nt) * 512);
            __syncthreads();

            #pragma unroll 2
            for (int kt = 0; kt < 8; ++kt) {
                const int cur = kt & 1;
                // issue B kc{2,3} of this kt
                #pragma unroll
                for (int kc = 0; kc < 2; ++kc)
                    #pragma unroll
                    for (int nt = 0; nt < 4; ++nt)
                        bp1[kc][nt] = *(const half8*)(Bl + ((kt * 4 + 2 + kc) * 8 + nt) * 512);
                // stage A(kt+1) into the other buffer
                if (kt < 7) {
                    const int k0 = (kt + 1) * 128;
                    #pragma unroll
                    for (int i = 0; i < 8; ++i) {
                        const int go = i * 4 * HDIM + ((i & 1) ? gO : gE);
                        __builtin_amdgcn_global_load_lds(
                            (GLOBAL_AS)(Abase + go + k0),
                            (LDS_AS)(&lA[1 - cur][lbase + i * 512]), 16, 0, 17);
                    }
                }
                const _Float16* bufA = &lA[cur][0];
                // compute kc 0,1 with bp0
                #pragma unroll
                for (int kc = 0; kc < 2; ++kc) {
                    const int slot = ((kc * 4 + quad) ^ rf) * 8;
                    half8 afr[4];
                    #pragma unroll
                    for (int mt = 0; mt < 4; ++mt)
                        afr[mt] = *(const half8*)(bufA + (wr * 64 + mt * 16 + lane15) * 128 + slot);
                    #pragma unroll
                    for (int mt = 0; mt < 4; ++mt)
                        #pragma unroll
                        for (int nt = 0; nt < 4; ++nt)
                            acc[mt][nt] = __builtin_amdgcn_mfma_f32_16x16x32_f16(
                                afr[mt], bp0[kc][nt], acc[mt][nt], 0, 0, 0);
                }
                // issue B kc{0,1} of kt+1
                if (kt < 7) {
                    #pragma unroll
                    for (int kc = 0; kc < 2; ++kc)
                        #pragma unroll
                        for (int nt = 0; nt < 4; ++nt)
                            bp0[kc][nt] = *(const half8*)(Bl + (((kt + 1) * 4 + kc) * 8 + nt) * 512);
                }
                // compute kc 2,3 with bp1
                #pragma unroll
                for (int kc = 0; kc < 2; ++kc) {
                    const int slot = (((kc + 2) * 4 + quad) ^ rf) * 8;
                    half8 afr[4];
                    #pragma unroll
                    for (int mt = 0; mt < 4; ++mt)
                        afr[mt] = *(const half8*)(bufA + (wr * 64 + mt * 16 + lane15) * 128 + slot);
                    #pragma unroll
                    for (int mt = 0; mt < 4; ++mt)
                        #pragma unroll
                        for (int nt = 0; nt < 4; ++nt)
                            acc[mt][nt] = __builtin_amdgcn_mfma_f32_16x16x32_f16(
                                afr[mt], bp1[kc][nt], acc[mt][nt], 0, 0, 0);
                }
                __syncthreads();
            }
        }

        // fused LSTM cell epilogue: lane holds all 4 gates of (batch m, unit j);
        // c stays in registers; h written through to MALL (sc0 sc1).
        #pragma unroll
        for (int mt = 0; mt < 4; ++mt) {
            #pragma unroll
            for (int r = 0; r < 4; ++r) {
                const int m = wr * 64 + mt * 16 + quad * 4 + r;
                const float xt = xr[mt][r];
                float pg = acc[mt][0][r] + xt * wgx_ + bg_;
                float pi = acc[mt][1][r] + xt * wix_ + bi_;
                float pf = acc[mt][2][r] + xt * wfx_ + bf_;
                float po = acc[mt][3][r] + xt * wox_ + bo_;
                float g  = fast_tanh(pg);
                float ii = fast_sig(pi);
                float ff = fast_sig(pf);
                float oo = fast_sig(po);
                float cn = g * ii + creg[mt][r] * ff;
                creg[mt][r] = cn;
                store_h_sys(&h_out[(size_t)(b0 + m) * HDIM + j], fast_tanh(cn) * oo);
            }
        }
    }
}

// ---------------------------------------------------------------------------
// logits = h_last @ w_ph^T + bias_p. One wave per batch row.
// (Reads h normally: dispatch-boundary acquire makes MALL data visible.)
// ---------------------------------------------------------------------------
__global__ void logits_kernel(const _Float16* __restrict__ h,
                              const float* __restrict__ wph,
                              const float* __restrict__ bp,
                              float* __restrict__ out) {
    const int w = (blockIdx.x * blockDim.x + threadIdx.x) >> 6; // 0..1023
    const int l = threadIdx.x & 63;
    float accv[NCLS];
    #pragma unroll
    for (int c = 0; c < NCLS; ++c) accv[c] = 0.f;
    for (int k = l; k < HDIM; k += 64) {
        float hv = (float)h[(size_t)w * HDIM + k];
        #pragma unroll
        for (int c = 0; c < NCLS; ++c)
            accv[c] += hv * wph[c * HDIM + k];
    }
    #pragma unroll
    for (int c = 0; c < NCLS; ++c) {
        float v = accv[c];
        #pragma unroll
        for (int off = 32; off > 0; off >>= 1)
            v += __shfl_down(v, off, 64);
        if (l == 0) out[w * NCLS + c] = v + bp[c];
    }
}

extern "C" void kernel_launch(void* const* d_in, const int* in_sizes, int n_in,
                              void* d_out, int out_size, void* d_ws, size_t ws_size,
                              hipStream_t stream) {
    const float* x   = (const float*)d_in[0];
    const float* wgx = (const float*)d_in[1];
    const float* wgh = (const float*)d_in[2];
    const float* wix = (const float*)d_in[3];
    const float* wih = (const float*)d_in[4];
    const float* wfx = (const float*)d_in[5];
    const float* wfh = (const float*)d_in[6];
    const float* wox = (const float*)d_in[7];
    const float* woh = (const float*)d_in[8];
    const float* wph = (const float*)d_in[9];
    const float* bg  = (const float*)d_in[10];
    const float* bi  = (const float*)d_in[11];
    const float* bf  = (const float*)d_in[12];
    const float* bo  = (const float*)d_in[13];
    const float* bp  = (const float*)d_in[14];
    float* out = (float*)d_out;

    char* ws = (char*)d_ws;
    _Float16* Wp    = (_Float16*)(ws);               // 0..8 MB (8192 x 1KB)
    _Float16* hbuf0 = (_Float16*)(ws + (8u << 20));  // 8..10 MB
    _Float16* hbuf1 = (_Float16*)(ws + (10u << 20)); // 10..12 MB
    int*      bar   = (int*)(ws + (12u << 20));      // barrier state (2 KB)

    prepack_kernel<<<8192, 64, 0, stream>>>(wgh, wih, wfh, woh, Wp, bar);

    PParams pp;
    pp.hb0 = hbuf0; pp.hb1 = hbuf1; pp.Wp = Wp; pp.x = x;
    pp.wgx = wgx; pp.wix = wix; pp.wfx = wfx; pp.wox = wox;
    pp.bg = bg; pp.bi = bi; pp.bf = bf; pp.bo = bo;
    pp.bar = bar;
    lstm_persist<<<NWG, 256, 0, stream>>>(pp);

    logits_kernel<<<256, 256, 0, stream>>>(hbuf1, wph, bp, out);  // t=127 -> hbuf1
}